// Round 3
// baseline (502.917 us; speedup 1.0000x reference)
//
#include <hip/hip_runtime.h>

#define NPOINTS 262144
#define SUMH 224
#define SUMW 221
#define NREG 500

// ---------- 64-lane wave reduce (region kernel only) ----------
__device__ __forceinline__ float rlane(float v, int l) {
  return __int_as_float(__builtin_amdgcn_readlane(__float_as_int(v), l));
}
template<int CTRL>
__device__ __forceinline__ float dpp_add(float x) {
  return x + __int_as_float(__builtin_amdgcn_update_dpp(0, __float_as_int(x), CTRL, 0xF, 0xF, false));
}
template<int CTRL>
__device__ __forceinline__ float dpp_max(float x) {
  return fmaxf(x, __int_as_float(__builtin_amdgcn_update_dpp(__float_as_int(x), __float_as_int(x), CTRL, 0xF, 0xF, false)));
}
__device__ __forceinline__ float wave_sum(float x) {
  x = dpp_add<0x111>(x); x = dpp_add<0x112>(x); x = dpp_add<0x114>(x);
  x = dpp_add<0x118>(x); x = dpp_add<0x142>(x); x = dpp_add<0x143>(x);
  return rlane(x, 63);
}
__device__ __forceinline__ float wave_max(float x) {
  x = dpp_max<0x111>(x); x = dpp_max<0x112>(x); x = dpp_max<0x114>(x);
  x = dpp_max<0x118>(x); x = dpp_max<0x142>(x); x = dpp_max<0x143>(x);
  return rlane(x, 63);
}

// ---------- 16-lane group primitives ----------
// group sum butterfly: quad xor1 (0xB1), xor2 (0x4E), row_half_mirror, row_mirror
__device__ __forceinline__ float grp_sum(float x) {
  x += __int_as_float(__builtin_amdgcn_update_dpp(0, __float_as_int(x), 0xB1,  0xF, 0xF, true));
  x += __int_as_float(__builtin_amdgcn_update_dpp(0, __float_as_int(x), 0x4E,  0xF, 0xF, true));
  x += __int_as_float(__builtin_amdgcn_update_dpp(0, __float_as_int(x), 0x141, 0xF, 0xF, true));
  x += __int_as_float(__builtin_amdgcn_update_dpp(0, __float_as_int(x), 0x140, 0xF, 0xF, true));
  return x;
}
__device__ __forceinline__ int grp_sum_i(int x) {
  x += __builtin_amdgcn_update_dpp(0, x, 0xB1,  0xF, 0xF, true);
  x += __builtin_amdgcn_update_dpp(0, x, 0x4E,  0xF, 0xF, true);
  x += __builtin_amdgcn_update_dpp(0, x, 0x141, 0xF, 0xF, true);
  x += __builtin_amdgcn_update_dpp(0, x, 0x140, 0xF, 0xF, true);
  return x;
}
// inclusive scan over the 16-lane DPP row: row_shr 1,2,4,8 (0-fill)
__device__ __forceinline__ float row_scan_incl(float x) {
  x += __int_as_float(__builtin_amdgcn_update_dpp(0, __float_as_int(x), 0x111, 0xF, 0xF, true));
  x += __int_as_float(__builtin_amdgcn_update_dpp(0, __float_as_int(x), 0x112, 0xF, 0xF, true));
  x += __int_as_float(__builtin_amdgcn_update_dpp(0, __float_as_int(x), 0x114, 0xF, 0xF, true));
  x += __int_as_float(__builtin_amdgcn_update_dpp(0, __float_as_int(x), 0x118, 0xF, 0xF, true));
  return x;
}
__device__ __forceinline__ float bperm(int lane, float v) {
  return __int_as_float(__builtin_amdgcn_ds_bpermute(lane << 2, __float_as_int(v)));
}
// uniform-index select among unrolled registers
template<int C>
__device__ __forceinline__ float sel(const float (&a)[C], int idx) {
  float r = a[0];
#pragma unroll
  for (int i = 1; i < C; ++i) r = (idx == i) ? a[i] : r;
  return r;
}

// ---------- Kernel 1: per-ROI tables ----------
// Per rix (stride SUMH floats), level slots {0..127, 128..191, 192..223}:
//   BL[j] = bin edge j (BL[0]=0, BL[n-1]=1)
//   HW[j] = 0.5*w_j      (0 for j=n-1)
//   HM[j] = 0.5*w_{j-1}  (0 for j=0)

template<int M, int SRC, int DST, int NB>
__device__ __forceinline__ void region_level(const float* __restrict__ wrow,
    float* __restrict__ BL, float* __restrict__ HW, float* __restrict__ HM,
    int lane, float* lds)
{
  float v0 = (lane < M) ? wrow[SRC + lane] : -1e30f;
  float v1 = -1e30f;
  if constexpr (NB == 128) { if (lane + 64 < M) v1 = wrow[SRC + lane + 64]; }
  float m = wave_max(fmaxf(v0, v1));
  float e0 = __expf(v0 - m);                 // 0 for padded slots
  float e1 = (NB == 128) ? __expf(v1 - m) : 0.0f;
  float s = wave_sum(e0 + e1);
  float inv = 1.0f / s;
  if (lane < NB) lds[lane] = e0;
  if constexpr (NB == 128) lds[lane + 64] = e1;
  __syncthreads();
  if (lane < NB) {
    HW[DST + lane] = 0.5f * e0 * inv;
    HM[DST + lane] = (lane == 0) ? 0.0f : 0.5f * lds[lane - 1] * inv;
  }
  if constexpr (NB == 128) {
    HW[DST + lane + 64] = 0.5f * e1 * inv;
    HM[DST + lane + 64] = 0.5f * lds[lane + 63] * inv;
  }
  if (lane == 0) {
    BL[DST] = 0.0f;
    float run = 0.0f;
    for (int k = 0; k < M; ++k) {
      run += lds[k];
      BL[DST + 1 + k] = (k == M - 1) ? 1.0f : run * inv;
    }
  }
  __syncthreads();
}

__global__ void __launch_bounds__(64) region_kernel(
    const int* __restrict__ roi, const float* __restrict__ wemb,
    float* __restrict__ wsBL, float* __restrict__ wsHW, float* __restrict__ wsHM)
{
  __shared__ float lds[128];
  int rix = blockIdx.x;
  int lane = threadIdx.x;
  int greg = roi[rix];
  const float* wrow = wemb + (size_t)greg * SUMW;
  float* BL = wsBL + (size_t)rix * SUMH;
  float* HW = wsHW + (size_t)rix * SUMH;
  float* HM = wsHM + (size_t)rix * SUMH;
  region_level<127,   0,   0, 128>(wrow, BL, HW, HM, lane, lds);
  region_level< 63, 127, 128,  64>(wrow, BL, HW, HM, lane, lds);
  region_level< 31, 190, 192,  32>(wrow, BL, HW, HM, lane, lds);
}

// ---------- Kernel 2: 4 points/wave, 16-lane groups; prep (independent) vs apply (dependent) ----------

template<int NB, int OFF, int C, int LOG2C>
struct Level {
  float he[C], bl[C], hw[C], Q[C];   // Q[i] = unnormalized cdf inclusive through global slot
  float larea, invarea;

  __device__ __forceinline__ void prep(const float* __restrict__ U,
      const float* __restrict__ D, const float* __restrict__ BLt,
      const float* __restrict__ HWt, const float* __restrict__ HMt, int s)
  {
    float t[C];
    if constexpr (C >= 4) {
#pragma unroll
      for (int v = 0; v < C / 4; ++v) {
        int c0 = OFF + (s * (C / 4) + v) * 4;
        float4 a = *(const float4*)(U   + c0);
        float4 b = *(const float4*)(D   + c0);
        float4 e = *(const float4*)(BLt + c0);
        float4 f = *(const float4*)(HWt + c0);
        float4 g = *(const float4*)(HMt + c0);
        he[4*v+0] = __expf(a.x + b.x); he[4*v+1] = __expf(a.y + b.y);
        he[4*v+2] = __expf(a.z + b.z); he[4*v+3] = __expf(a.w + b.w);
        bl[4*v+0]=e.x; bl[4*v+1]=e.y; bl[4*v+2]=e.z; bl[4*v+3]=e.w;
        hw[4*v+0]=f.x; hw[4*v+1]=f.y; hw[4*v+2]=f.z; hw[4*v+3]=f.w;
        t[4*v+0] = he[4*v+0]*(f.x+g.x); t[4*v+1] = he[4*v+1]*(f.y+g.y);
        t[4*v+2] = he[4*v+2]*(f.z+g.z); t[4*v+3] = he[4*v+3]*(f.w+g.w);
      }
    } else {
      int c0 = OFF + s * 2;
      float2 a = *(const float2*)(U   + c0);
      float2 b = *(const float2*)(D   + c0);
      float2 e = *(const float2*)(BLt + c0);
      float2 f = *(const float2*)(HWt + c0);
      float2 g = *(const float2*)(HMt + c0);
      he[0] = __expf(a.x + b.x); he[1] = __expf(a.y + b.y);
      bl[0]=e.x; bl[1]=e.y; hw[0]=f.x; hw[1]=f.y;
      t[0] = he[0]*(f.x+g.x); t[1] = he[1]*(f.y+g.y);
    }
    // in-lane inclusive prefix
    float p = 0.0f;
#pragma unroll
    for (int i = 0; i < C; ++i) { p += t[i]; Q[i] = p; }
    // cross-lane: inclusive scan of lane totals over the 16-lane row
    float sc = row_scan_incl(p);
    float excl = sc - p;
#pragma unroll
    for (int i = 0; i < C; ++i) Q[i] += excl;
    float area = grp_sum(p);
    larea = __log2f(area);
    invarea = __builtin_amdgcn_rcpf(area);
  }

  __device__ __forceinline__ void apply(float& xv, float& logdet, int grp, int s) {
    int cnt = 0;
#pragma unroll
    for (int i = 0; i < C; ++i) cnt += (bl[i] < xv) ? 1 : 0;
    cnt = grp_sum_i(cnt);
    int bi = min(max(cnt - 1, 0), NB - 2);
    int sl0 = bi & (C - 1);
    int ln0 = (grp << 4) + (bi >> LOG2C);
    int bj = bi + 1;
    int sl1 = bj & (C - 1);
    int ln1 = (grp << 4) + (bj >> LOG2C);
    // in-lane uniform-index selects, then pull from the owning lane
    float qs  = sel<C>(Q,  sl0);
    float bls = sel<C>(bl, sl0);
    float hws = sel<C>(hw, sl0);
    float hes = sel<C>(he, sl0);
    float he1 = sel<C>(he, sl1);
    float q_b  = bperm(ln0, qs);
    float bl_b = bperm(ln0, bls);
    float hw_b = bperm(ln0, hws);
    float hl   = bperm(ln0, hes);
    float hr   = bperm(ln1, he1);
    float part = q_b - hl * hw_b;          // unnormalized cdf at left edge of bin bi
    float inw = 2.0f * hw_b;
    float alpha = (xv - bl_b) * __builtin_amdgcn_rcpf(inw);
    float dh = hr - hl;
    xv = ((0.5f * dh * alpha + hl) * alpha * inw + part) * invarea;
    logdet += (__log2f(alpha * dh + hl) - larea) * 0.69314718055994531f;
  }
};

__global__ void __launch_bounds__(256) spline_kernel(
    const float* __restrict__ x, const int* __restrict__ roi,
    const int* __restrict__ lix, const float* __restrict__ delta,
    const float* __restrict__ hemb,
    const float* __restrict__ wsBL, const float* __restrict__ wsHW,
    const float* __restrict__ wsHM, float* __restrict__ out)
{
  int tid  = (int)(blockIdx.x * blockDim.x + threadIdx.x);
  int wid  = tid >> 6;
  int lane = (int)(threadIdx.x & 63);
  int grp  = lane >> 4;            // 4 points per wave
  int s    = lane & 15;            // 16-lane group, lanes <-> columns
  int pid  = wid * 4 + grp;

  float xv = x[pid];               // group-uniform
  int r    = lix[pid];
  int greg = roi[r];
  const float* U   = hemb  + (size_t)greg * SUMH;
  const float* D   = delta + (size_t)pid  * SUMH;
  const float* BLt = wsBL  + (size_t)r    * SUMH;
  const float* HWt = wsHW  + (size_t)r    * SUMH;
  const float* HMt = wsHM  + (size_t)r    * SUMH;

  Level<128,   0, 8, 3> L0;
  Level< 64, 128, 4, 2> L1;
  Level< 32, 192, 2, 1> L2;
  // independent phase: all loads + exp + prefix/area for all levels
  L0.prep(U, D, BLt, HWt, HMt, s);
  L1.prep(U, D, BLt, HWt, HMt, s);
  L2.prep(U, D, BLt, HWt, HMt, s);
  // dependent phase: register-only chain
  float logdet = 0.0f;
  L0.apply(xv, logdet, grp, s);
  L1.apply(xv, logdet, grp, s);
  L2.apply(xv, logdet, grp, s);

  if (s == 0) {
    out[pid] = xv;
    out[NPOINTS + pid] = logdet;
  }
}

// ---------- launch ----------

extern "C" void kernel_launch(void* const* d_in, const int* in_sizes, int n_in,
                              void* d_out, int out_size, void* d_ws, size_t ws_size,
                              hipStream_t stream) {
  const float* x     = (const float*)d_in[0];
  const int*   roi   = (const int*)  d_in[1];
  const int*   lix   = (const int*)  d_in[2];
  const float* delta = (const float*)d_in[3];
  const float* hemb  = (const float*)d_in[4];
  const float* wemb  = (const float*)d_in[5];

  float* wsBL = (float*)d_ws;                    // [500][224]
  float* wsHW = wsBL + (size_t)NREG * SUMH;      // [500][224]
  float* wsHM = wsHW + (size_t)NREG * SUMH;      // [500][224]

  region_kernel<<<NREG, 64, 0, stream>>>(roi, wemb, wsBL, wsHW, wsHM);
  spline_kernel<<<NPOINTS / 16, 256, 0, stream>>>(x, roi, lix, delta, hemb,
                                                  wsBL, wsHW, wsHM, (float*)d_out);
}

// Round 4
// 358.729 us; speedup vs baseline: 1.4019x; 1.4019x over previous
//
#include <hip/hip_runtime.h>

#define NPOINTS 262144
#define SUMH 224
#define SUMW 221
#define NREG 500

// ---------- DPP helpers ----------
__device__ __forceinline__ float rlane(float v, int l) {
  return __int_as_float(__builtin_amdgcn_readlane(__float_as_int(v), l));
}
template<int CTRL>
__device__ __forceinline__ float dpp0(float x) {   // 0-fill on invalid
  return __int_as_float(__builtin_amdgcn_update_dpp(0, __float_as_int(x), CTRL, 0xF, 0xF, true));
}
template<int CTRL, int RM>
__device__ __forceinline__ float dpp_rm(float x) { // row-masked, old=0
  return __int_as_float(__builtin_amdgcn_update_dpp(0, __float_as_int(x), CTRL, RM, 0xF, false));
}
template<int CTRL>
__device__ __forceinline__ float dpp_max_(float x) {
  return fmaxf(x, __int_as_float(__builtin_amdgcn_update_dpp(__float_as_int(x), __float_as_int(x), CTRL, 0xF, 0xF, false)));
}
// 64-lane reduce (region kernel)
__device__ __forceinline__ float wave_sum(float x) {
  x += dpp0<0x111>(x); x += dpp0<0x112>(x); x += dpp0<0x114>(x); x += dpp0<0x118>(x);
  x += dpp_rm<0x142, 0xA>(x); x += dpp_rm<0x143, 0xC>(x);
  return rlane(x, 63);
}
__device__ __forceinline__ float wave_max(float x) {
  x = dpp_max_<0x111>(x); x = dpp_max_<0x112>(x); x = dpp_max_<0x114>(x);
  x = dpp_max_<0x118>(x); x = dpp_max_<0x142>(x); x = dpp_max_<0x143>(x);
  return rlane(x, 63);
}
// 64-lane inclusive scan (region kernel)
__device__ __forceinline__ float wave_scan_incl(float x) {
  x += dpp0<0x111>(x); x += dpp0<0x112>(x); x += dpp0<0x114>(x); x += dpp0<0x118>(x);
  x += dpp_rm<0x142, 0xA>(x);   // row_bcast:15 -> rows 1,3
  x += dpp_rm<0x143, 0xC>(x);   // row_bcast:31 -> rows 2,3
  return x;
}
// 16-lane group sum butterfly (spline kernel)
__device__ __forceinline__ float grp_sum(float x) {
  x += dpp0<0xB1>(x);    // quad_perm xor1
  x += dpp0<0x4E>(x);    // quad_perm xor2
  x += dpp0<0x141>(x);   // row_half_mirror
  x += dpp0<0x140>(x);   // row_mirror
  return x;
}

// ---------- Kernel 1: per-ROI tables ----------
// Per rix (stride SUMH floats), level slots {0..127, 128..191, 192..223}:
//   BL[j] = bin edge j (BL[0]=0, BL[n-1]=1)
//   HW[j] = 0.5*w_j                (0 for j=n-1)
//   HS[j] = 0.5*(w_{j-1} + w_j)    (trapezoid weight; w_{-1}=w_{n-1}=0)

template<int M, int SRC, int DST, int NB>
__device__ __forceinline__ void region_level(const float* __restrict__ wrow,
    float* __restrict__ BL, float* __restrict__ HW, float* __restrict__ HS,
    int lane, float* lds)
{
  float v0 = (lane < M) ? wrow[SRC + lane] : -1e30f;
  float v1 = -1e30f;
  if constexpr (NB == 128) { if (lane + 64 < M) v1 = wrow[SRC + lane + 64]; }
  float m = wave_max(fmaxf(v0, v1));
  float e0 = __expf(v0 - m);                 // 0 for padded slots
  float e1 = (NB == 128) ? __expf(v1 - m) : 0.0f;
  float s = wave_sum(e0 + e1);
  float inv = 1.0f / s;
  if (lane < NB) lds[lane] = e0;
  if constexpr (NB == 128) lds[lane + 64] = e1;
  __syncthreads();
  if (lane < NB) {
    HW[DST + lane] = 0.5f * e0 * inv;
    float prev = (lane == 0) ? 0.0f : lds[lane - 1];
    HS[DST + lane] = 0.5f * (e0 + prev) * inv;
  }
  if constexpr (NB == 128) {
    HW[DST + lane + 64] = 0.5f * e1 * inv;
    HS[DST + lane + 64] = 0.5f * (e1 + lds[lane + 63]) * inv;
  }
  // bin edges via wave scan (no serial loop)
  float incl0 = wave_scan_incl(e0);
  if (lane == 0) BL[DST] = 0.0f;
  if (lane < M) BL[DST + 1 + lane] = (lane == M - 1) ? 1.0f : incl0 * inv;
  if constexpr (NB == 128) {
    float incl1 = wave_scan_incl(e1) + rlane(incl0, 63);
    int k = 64 + lane;
    if (k < M) BL[DST + 1 + k] = (k == M - 1) ? 1.0f : incl1 * inv;
  }
  __syncthreads();
}

__global__ void __launch_bounds__(64) region_kernel(
    const int* __restrict__ roi, const float* __restrict__ wemb,
    float* __restrict__ wsBL, float* __restrict__ wsHW, float* __restrict__ wsHS)
{
  __shared__ float lds[128];
  int rix = blockIdx.x;
  int lane = threadIdx.x;
  int greg = roi[rix];
  const float* wrow = wemb + (size_t)greg * SUMW;
  float* BL = wsBL + (size_t)rix * SUMH;
  float* HW = wsHW + (size_t)rix * SUMH;
  float* HS = wsHS + (size_t)rix * SUMH;
  region_level<127,   0,   0, 128>(wrow, BL, HW, HS, lane, lds);
  region_level< 63, 127, 128,  64>(wrow, BL, HW, HS, lane, lds);
  region_level< 31, 190, 192,  32>(wrow, BL, HW, HS, lane, lds);
}

// ---------- Kernel 2: 4 points/wave, 16-lane groups, masked-reduction apply ----------
// No dynamic indexing anywhere: boundary values extracted via one-hot masked sums.

template<int NB, int OFF, int C>
struct Lv {
  float he[C], t[C], bl[C], hw[C];
  float larea, invarea;

  __device__ __forceinline__ void prep(const float* __restrict__ U,
      const float* __restrict__ D, const float* __restrict__ BLt,
      const float* __restrict__ HWt, const float* __restrict__ HSt, int s)
  {
    if constexpr (C >= 4) {
#pragma unroll
      for (int v = 0; v < C / 4; ++v) {
        int c0 = OFF + (s * (C / 4) + v) * 4;
        float4 a = *(const float4*)(U   + c0);
        float4 b = *(const float4*)(D   + c0);
        float4 e = *(const float4*)(BLt + c0);
        float4 f = *(const float4*)(HWt + c0);
        float4 g = *(const float4*)(HSt + c0);
        he[4*v+0] = __expf(a.x + b.x); he[4*v+1] = __expf(a.y + b.y);
        he[4*v+2] = __expf(a.z + b.z); he[4*v+3] = __expf(a.w + b.w);
        t[4*v+0] = he[4*v+0] * g.x; t[4*v+1] = he[4*v+1] * g.y;
        t[4*v+2] = he[4*v+2] * g.z; t[4*v+3] = he[4*v+3] * g.w;
        bl[4*v+0]=e.x; bl[4*v+1]=e.y; bl[4*v+2]=e.z; bl[4*v+3]=e.w;
        hw[4*v+0]=f.x; hw[4*v+1]=f.y; hw[4*v+2]=f.z; hw[4*v+3]=f.w;
      }
    } else {
      int c0 = OFF + s * 2;
      float2 a = *(const float2*)(U   + c0);
      float2 b = *(const float2*)(D   + c0);
      float2 e = *(const float2*)(BLt + c0);
      float2 f = *(const float2*)(HWt + c0);
      float2 g = *(const float2*)(HSt + c0);
      he[0] = __expf(a.x + b.x); he[1] = __expf(a.y + b.y);
      t[0] = he[0] * g.x; t[1] = he[1] * g.y;
      bl[0]=e.x; bl[1]=e.y; hw[0]=f.x; hw[1]=f.y;
    }
    float asum = 0.0f;
#pragma unroll
    for (int i = 0; i < C; ++i) asum += t[i];
    float area = grp_sum(asum);
    larea = __log2f(area);
    invarea = __builtin_amdgcn_rcpf(area);
  }

  __device__ __forceinline__ void apply(float& xv, float& logdet, int s) {
    float f[C];
#pragma unroll
    for (int i = 0; i < C; ++i) f[i] = (bl[i] < xv) ? 1.0f : 0.0f;
    if (s == 0)  f[0]     = 1.0f;   // edge 0 always counted (clamp-low)
    if (s == 15) f[C - 1] = 0.0f;   // edge NB-1 never counted (clamp-high)
    // neighbor firsts from next lane (0 at lane 15 -> masked out anyway)
    float fN  = dpp0<0x101>(f[0]);   // row_shl:1
    float heN = dpp0<0x101>(he[0]);
    float hl = 0.0f, hr = 0.0f, loc = 0.0f, hwm = 0.0f, pt = 0.0f;
#pragma unroll
    for (int i = 0; i < C; ++i) {
      float fnext  = (i < C - 1) ? f[i + 1]  : fN;
      float henext = (i < C - 1) ? he[i + 1] : heN;
      float mi = f[i] * (1.0f - fnext);   // one-hot at bin bi
      hl  += he[i] * mi;
      hr  += henext * mi;
      loc += bl[i] * mi;
      hwm += hw[i] * mi;
      pt  += t[i] * f[i];                 // inclusive trapezoid sum through bi
    }
    hl  = grp_sum(hl);
    hr  = grp_sum(hr);
    loc = grp_sum(loc);
    hwm = grp_sum(hwm);
    pt  = grp_sum(pt);
    float part = pt - hl * hwm;           // unnormalized cdf at left edge of bin
    float inw = 2.0f * hwm;
    float alpha = (xv - loc) * __builtin_amdgcn_rcpf(inw);
    float dh = hr - hl;
    xv = ((0.5f * dh * alpha + hl) * alpha * inw + part) * invarea;
    logdet += (__log2f(alpha * dh + hl) - larea) * 0.69314718055994531f;
  }
};

__global__ void __launch_bounds__(256) spline_kernel(
    const float* __restrict__ x, const int* __restrict__ roi,
    const int* __restrict__ lix, const float* __restrict__ delta,
    const float* __restrict__ hemb,
    const float* __restrict__ wsBL, const float* __restrict__ wsHW,
    const float* __restrict__ wsHS, float* __restrict__ out)
{
  int tid  = (int)(blockIdx.x * blockDim.x + threadIdx.x);
  int wid  = tid >> 6;
  int lane = (int)(threadIdx.x & 63);
  int grp  = lane >> 4;            // 4 points per wave
  int s    = lane & 15;            // 16-lane group, lanes <-> columns
  int pid  = wid * 4 + grp;

  float xv = x[pid];               // group-uniform
  int r    = lix[pid];
  int greg = roi[r];
  const float* U   = hemb  + (size_t)greg * SUMH;
  const float* D   = delta + (size_t)pid  * SUMH;
  const float* BLt = wsBL  + (size_t)r    * SUMH;
  const float* HWt = wsHW  + (size_t)r    * SUMH;
  const float* HSt = wsHS  + (size_t)r    * SUMH;

  Lv<128,   0, 8> L0;
  Lv< 64, 128, 4> L1;
  Lv< 32, 192, 2> L2;
  float logdet = 0.0f;
  // rolling pipeline: next level's loads in flight during current apply
  L0.prep(U, D, BLt, HWt, HSt, s);
  L1.prep(U, D, BLt, HWt, HSt, s);
  L0.apply(xv, logdet, s);
  L2.prep(U, D, BLt, HWt, HSt, s);
  L1.apply(xv, logdet, s);
  L2.apply(xv, logdet, s);

  if (s == 0) {
    out[pid] = xv;
    out[NPOINTS + pid] = logdet;
  }
}

// ---------- launch ----------

extern "C" void kernel_launch(void* const* d_in, const int* in_sizes, int n_in,
                              void* d_out, int out_size, void* d_ws, size_t ws_size,
                              hipStream_t stream) {
  const float* x     = (const float*)d_in[0];
  const int*   roi   = (const int*)  d_in[1];
  const int*   lix   = (const int*)  d_in[2];
  const float* delta = (const float*)d_in[3];
  const float* hemb  = (const float*)d_in[4];
  const float* wemb  = (const float*)d_in[5];

  float* wsBL = (float*)d_ws;                    // [500][224]
  float* wsHW = wsBL + (size_t)NREG * SUMH;      // [500][224]
  float* wsHS = wsHW + (size_t)NREG * SUMH;      // [500][224]

  region_kernel<<<NREG, 64, 0, stream>>>(roi, wemb, wsBL, wsHW, wsHS);
  spline_kernel<<<NPOINTS / 16, 256, 0, stream>>>(x, roi, lix, delta, hemb,
                                                  wsBL, wsHW, wsHS, (float*)d_out);
}